// Round 5
// baseline (208.353 us; speedup 1.0000x reference)
//
#include <hip/hip_runtime.h>

#define L 1600
#define C 256
#define HW 40
#define HP 56            // padded spatial (40 + 2*8)
#define HP2 (HP * HP)    // 3136
#define KW 17
#define K2 289
#define HEADS 8
#define NJ (K2 * 256)    // 73984 flat window elements
#define MG 8             // output channels per attnD block
#define SCALE 0.17677669529663687f  // 32^-0.5

// workspace layout (in floats); qT is reused as outT (disjoint lifetimes)
#define OFF_TAB   0
#define OFF_INV   (OFF_TAB + 2 * NJ)
#define OFF_QT    (OFF_INV + HEADS * L)
#define OFF_K     (OFF_QT + 409600)
#define OFF_V     (OFF_K + 802816)
#define OFF_P     (OFF_V + 802816)

__global__ __launch_bounds__(256) void zero_kernel(float4* __restrict__ p, int n4) {
    int i = blockIdx.x * 256 + threadIdx.x;
    if (i < n4) p[i] = make_float4(0.f, 0.f, 0.f, 0.f);
}

// offtab[j] = image offset of flat-window element j (j = c*289 + p)
__global__ __launch_bounds__(256) void addr_kernel(int* __restrict__ offtab) {
    int j = blockIdx.x * 256 + threadIdx.x;   // grid covers exactly NJ
    int c = j / K2;
    int p = j - c * K2;
    int dr = p / KW;
    int ds = p - dr * KW;
    offtab[j] = c * HP2 + dr * HP + ds;
}

// qkv[l, oc] = sum_c x[c, l] * w[oc, c] + b[oc]
// q (scaled) -> qT[m][l];  k/v -> padded images
__global__ __launch_bounds__(256) void qkv_gemm(const float* __restrict__ x,
                                                const float* __restrict__ w,
                                                const float* __restrict__ bias,
                                                float* __restrict__ qT,
                                                float* __restrict__ kpad,
                                                float* __restrict__ vpad) {
    __shared__ float As[16][68];  // A[c][l]
    __shared__ float Bs[16][68];  // B[c][oc]
    const int l0 = blockIdx.x * 64;
    const int oc0 = blockIdx.y * 64;
    const int tid = threadIdx.x;
    const int tx = tid & 15;   // oc quad
    const int ty = tid >> 4;   // l quad
    float acc[4][4] = {};
    for (int c0 = 0; c0 < C; c0 += 16) {
#pragma unroll
        for (int i = 0; i < 4; ++i) {
            int idx = i * 256 + tid;
            int cc = idx >> 6, ll = idx & 63;
            As[cc][ll] = x[(c0 + cc) * L + l0 + ll];
        }
#pragma unroll
        for (int i = 0; i < 4; ++i) {
            int idx = i * 256 + tid;
            int cc = idx & 15, oo = idx >> 4;
            Bs[cc][oo] = w[(oc0 + oo) * C + c0 + cc];
        }
        __syncthreads();
#pragma unroll
        for (int kk = 0; kk < 16; ++kk) {
            float4 a = *(const float4*)&As[kk][ty * 4];
            float4 b = *(const float4*)&Bs[kk][tx * 4];
            float av[4] = {a.x, a.y, a.z, a.w};
            float bv[4] = {b.x, b.y, b.z, b.w};
#pragma unroll
            for (int i = 0; i < 4; ++i)
#pragma unroll
                for (int j = 0; j < 4; ++j)
                    acc[i][j] = fmaf(av[i], bv[j], acc[i][j]);
        }
        __syncthreads();
    }
    const int lbase = l0 + ty * 4;
    const int ocbase = oc0 + tx * 4;
    if (oc0 < 256) {
#pragma unroll
        for (int j = 0; j < 4; ++j) {
            int oc = ocbase + j;
            float b = bias[oc];
            float4 v = make_float4((acc[0][j] + b) * SCALE, (acc[1][j] + b) * SCALE,
                                   (acc[2][j] + b) * SCALE, (acc[3][j] + b) * SCALE);
            *(float4*)&qT[oc * L + lbase] = v;
        }
    } else {
        float* dst = (oc0 < 512) ? kpad : vpad;
        const int cb = ocbase - ((oc0 < 512) ? 256 : 512);
#pragma unroll
        for (int i = 0; i < 4; ++i) {
            int l = lbase + i;
            int r = l / HW, s = l % HW;
            int base = (r + 8) * HP + (s + 8);
#pragma unroll
            for (int j = 0; j < 4; ++j)
                dst[(cb + j) * HP2 + base] = acc[i][j] + bias[ocbase + j];
        }
    }
}

// Phase B: logits. Block-uniform (h, n1-chunk); lanes = n. Gather offsets are
// scalar (offtab, uniform index); q in 32 regs reused across the chunk;
// K loads coalesced over consecutive n. P[n1*8+h][n] = <q, K_window>.
__global__ __launch_bounds__(256) void attnB(const float* __restrict__ qT,
                                             const float* __restrict__ kpad,
                                             const int* __restrict__ offtab,
                                             float* __restrict__ P) {
    const int h = blockIdx.y;
    const int n = blockIdx.z * 256 + threadIdx.x;
    const bool valid = (n < L);
    const int nn = valid ? n : 0;
    const int basen = (nn / HW) * HP + (nn % HW);
    float q[32];
#pragma unroll
    for (int k = 0; k < 32; ++k) q[k] = qT[(h * 32 + k) * L + nn];
    const float* kb = kpad + basen;
    int n1 = blockIdx.x * 17;
    for (int b = 0; b < 17; ++b, ++n1) {
        const int j0 = n1 * 256 + h * 32;   // uniform
        float a0 = 0.f, a1 = 0.f, a2 = 0.f, a3 = 0.f;
#pragma unroll
        for (int k = 0; k < 8; ++k) {
            a0 = fmaf(q[k],      kb[offtab[j0 + k]],      a0);
            a1 = fmaf(q[k + 8],  kb[offtab[j0 + k + 8]],  a1);
            a2 = fmaf(q[k + 16], kb[offtab[j0 + k + 16]], a2);
            a3 = fmaf(q[k + 24], kb[offtab[j0 + k + 24]], a3);
        }
        if (valid) P[(n1 * 8 + h) * L + n] = (a0 + a1) + (a2 + a3);
    }
}

// Phase C: per (n, h): max over n1, P := exp(x-max)*mask (UN-normalized),
// inv[h][n] = 1/sum(exp) (sum over ALL slots, pre-mask, as in reference).
__global__ __launch_bounds__(256) void attnC(float* __restrict__ P,
                                             float* __restrict__ inv) {
    __shared__ float red[4][64];
    const int t = threadIdx.x;
    const int h = blockIdx.y;
    const int nl = t & 63;
    const int n = blockIdx.x * 64 + nl;
    const int qtr = t >> 6;
    const int n1lo = qtr * 73;
    const int n1hi = (n1lo + 73 < K2) ? n1lo + 73 : K2;
    const int nr = n / HW, nc = n % HW;
    float mx = -1e30f;
    for (int n1 = n1lo; n1 < n1hi; ++n1)
        mx = fmaxf(mx, P[(n1 * 8 + h) * L + n]);
    red[qtr][nl] = mx;
    __syncthreads();
    mx = fmaxf(fmaxf(red[0][nl], red[1][nl]), fmaxf(red[2][nl], red[3][nl]));
    __syncthreads();
    float s = 0.f;
    for (int n1 = n1lo; n1 < n1hi; ++n1) {
        float v = P[(n1 * 8 + h) * L + n];
        float e = __expf(v - mx);
        s += e;
        int dr = n1 / KW, ds = n1 - dr * KW;       // uniform per iter
        unsigned rr = (unsigned)(nr + dr - 8), ss = (unsigned)(nc + ds - 8);
        float msk = (rr < HW && ss < HW) ? 1.f : 0.f;
        P[(n1 * 8 + h) * L + n] = e * msk;
    }
    red[qtr][nl] = s;
    __syncthreads();
    if (qtr == 0)
        inv[h * L + n] = 1.f / (red[0][nl] + red[1][nl] + red[2][nl] + red[3][nl]);
}

// Phase D: out2T[m][n] = inv[h][n] * sum_n1 P[n1*8+h][n] * V_window.
// MG=8 channels per block: P loaded once per 8 FMAs; offsets for the group
// are contiguous in offtab (j = n1*256 + m) -> scalar-load friendly.
__global__ __launch_bounds__(128) void attnD(const float* __restrict__ P,
                                             const float* __restrict__ vpad,
                                             const int* __restrict__ offtab,
                                             const float* __restrict__ inv,
                                             float* __restrict__ outT) {
    const int m0 = blockIdx.x * MG;
    const int h = m0 >> 5;
    const int n = blockIdx.y * 128 + threadIdx.x;
    const bool valid = (n < L);
    const int nn = valid ? n : 0;
    const int basen = (nn / HW) * HP + (nn % HW);
    const float* vb = vpad + basen;
    const float* Ph = P + h * L + nn;
    float acc[MG] = {};
#pragma unroll 4
    for (int n1 = 0; n1 < K2; ++n1) {
        const float p = Ph[n1 * (8 * L)];
        const int* tb = offtab + n1 * 256 + m0;   // 8 contiguous uniform ints
#pragma unroll
        for (int i = 0; i < MG; ++i)
            acc[i] = fmaf(p, vb[tb[i]], acc[i]);
    }
    if (valid) {
        const float iv = inv[h * L + n];
#pragma unroll
        for (int i = 0; i < MG; ++i)
            outT[(m0 + i) * L + n] = acc[i] * iv;
    }
}

// out[oc*1600 + l] = sum_c outT[c][l] * w[oc, c] + b[oc]
__global__ __launch_bounds__(256) void proj_gemm(const float* __restrict__ aT,
                                                 const float* __restrict__ w,
                                                 const float* __restrict__ bias,
                                                 float* __restrict__ out) {
    __shared__ float As[16][68];  // A[c][l]
    __shared__ float Bs[16][68];  // B[c][oc]
    const int l0 = blockIdx.x * 64;
    const int oc0 = blockIdx.y * 64;
    const int tid = threadIdx.x;
    const int tx = tid & 15;   // oc quad
    const int ty = tid >> 4;   // l quad
    float acc[4][4] = {};      // [i: l][j: oc]
    for (int c0 = 0; c0 < C; c0 += 16) {
#pragma unroll
        for (int i = 0; i < 4; ++i) {
            int idx = i * 256 + tid;
            int cc = idx >> 6, ll = idx & 63;
            As[cc][ll] = aT[(c0 + cc) * L + l0 + ll];
        }
#pragma unroll
        for (int i = 0; i < 4; ++i) {
            int idx = i * 256 + tid;
            int cc = idx & 15, oo = idx >> 4;
            Bs[cc][oo] = w[(oc0 + oo) * C + c0 + cc];
        }
        __syncthreads();
#pragma unroll
        for (int kk = 0; kk < 16; ++kk) {
            float4 a = *(const float4*)&As[kk][ty * 4];
            float4 b = *(const float4*)&Bs[kk][tx * 4];
            float av[4] = {a.x, a.y, a.z, a.w};
            float bv[4] = {b.x, b.y, b.z, b.w};
#pragma unroll
            for (int i = 0; i < 4; ++i)
#pragma unroll
                for (int j = 0; j < 4; ++j)
                    acc[i][j] = fmaf(av[i], bv[j], acc[i][j]);
        }
        __syncthreads();
    }
    const int lbase = l0 + ty * 4;
#pragma unroll
    for (int j = 0; j < 4; ++j) {
        int oc = oc0 + tx * 4 + j;
        float bp = bias[oc];
        float4 v = make_float4(acc[0][j] + bp, acc[1][j] + bp,
                               acc[2][j] + bp, acc[3][j] + bp);
        *(float4*)&out[oc * L + lbase] = v;
    }
}

extern "C" void kernel_launch(void* const* d_in, const int* in_sizes, int n_in,
                              void* d_out, int out_size, void* d_ws, size_t ws_size,
                              hipStream_t stream) {
    const float* x      = (const float*)d_in[0];
    const float* w_qkv  = (const float*)d_in[1];
    const float* b_qkv  = (const float*)d_in[2];
    const float* w_proj = (const float*)d_in[3];
    const float* b_proj = (const float*)d_in[4];
    float* out = (float*)d_out;
    float* ws = (float*)d_ws;
    int*   offtab = (int*)(ws + OFF_TAB);
    float* inv  = ws + OFF_INV;
    float* qT   = ws + OFF_QT;   // reused as outT after attnB finishes
    float* kpad = ws + OFF_K;
    float* vpad = ws + OFF_V;
    float* P    = ws + OFF_P;

    // zero padded K/V images (contiguous: 2 * 802816 floats)
    const int n4 = (2 * 802816) / 4;
    zero_kernel<<<n4 / 256, 256, 0, stream>>>((float4*)kpad, n4);
    addr_kernel<<<NJ / 256, 256, 0, stream>>>(offtab);

    qkv_gemm<<<dim3(25, 12), 256, 0, stream>>>(x, w_qkv, b_qkv, qT, kpad, vpad);
    attnB<<<dim3(17, 8, 7), 256, 0, stream>>>(qT, kpad, offtab, P);
    attnC<<<dim3(25, 8), 256, 0, stream>>>(P, inv);
    attnD<<<dim3(32, 13), 128, 0, stream>>>(P, vpad, offtab, inv, qT);
    proj_gemm<<<dim3(25, 4), 256, 0, stream>>>(qT, w_proj, b_proj, out);
}

// Round 7
// 158.009 us; speedup vs baseline: 1.3186x; 1.3186x over previous
//
#include <hip/hip_runtime.h>

#define L 1600
#define C 256
#define HW 40
#define HP 56            // padded spatial (40 + 2*8)
#define HP2 (HP * HP)    // 3136
#define KW 17
#define K2 289
#define HEADS 8
#define NJ (K2 * 256)    // 73984 flat window elements
#define SCALE 0.17677669529663687f  // 32^-0.5

// workspace layout (in floats); qT is reused as outT (disjoint lifetimes)
#define OFF_TAB   0
#define OFF_INV   (OFF_TAB + 2 * NJ)
#define OFF_QT    (OFF_INV + HEADS * L)
#define OFF_K     (OFF_QT + 409600)
#define OFF_V     (OFF_K + 802816)
#define OFF_P     (OFF_V + 802816)

__global__ __launch_bounds__(256) void zero_kernel(float4* __restrict__ p, int n4) {
    int i = blockIdx.x * 256 + threadIdx.x;
    if (i < n4) p[i] = make_float4(0.f, 0.f, 0.f, 0.f);
}

// offtab[j] = image offset of flat-window element j (j = c*289 + p)
__global__ __launch_bounds__(256) void addr_kernel(int* __restrict__ offtab) {
    int j = blockIdx.x * 256 + threadIdx.x;   // grid covers exactly NJ
    int c = j / K2;
    int p = j - c * K2;
    int dr = p / KW;
    int ds = p - dr * KW;
    offtab[j] = c * HP2 + dr * HP + ds;
}

// qkv[l, oc] = sum_c x[c, l] * w[oc, c] + b[oc]
// q (scaled) -> qT[m][l];  k/v -> padded images
__global__ __launch_bounds__(256) void qkv_gemm(const float* __restrict__ x,
                                                const float* __restrict__ w,
                                                const float* __restrict__ bias,
                                                float* __restrict__ qT,
                                                float* __restrict__ kpad,
                                                float* __restrict__ vpad) {
    __shared__ float As[16][68];  // A[c][l]
    __shared__ float Bs[16][68];  // B[c][oc]
    const int l0 = blockIdx.x * 64;
    const int oc0 = blockIdx.y * 64;
    const int tid = threadIdx.x;
    const int tx = tid & 15;   // oc quad
    const int ty = tid >> 4;   // l quad
    float acc[4][4] = {};
    for (int c0 = 0; c0 < C; c0 += 16) {
#pragma unroll
        for (int i = 0; i < 4; ++i) {
            int idx = i * 256 + tid;
            int cc = idx >> 6, ll = idx & 63;
            As[cc][ll] = x[(c0 + cc) * L + l0 + ll];
        }
#pragma unroll
        for (int i = 0; i < 4; ++i) {
            int idx = i * 256 + tid;
            int cc = idx & 15, oo = idx >> 4;
            Bs[cc][oo] = w[(oc0 + oo) * C + c0 + cc];
        }
        __syncthreads();
#pragma unroll
        for (int kk = 0; kk < 16; ++kk) {
            float4 a = *(const float4*)&As[kk][ty * 4];
            float4 b = *(const float4*)&Bs[kk][tx * 4];
            float av[4] = {a.x, a.y, a.z, a.w};
            float bv[4] = {b.x, b.y, b.z, b.w};
#pragma unroll
            for (int i = 0; i < 4; ++i)
#pragma unroll
                for (int j = 0; j < 4; ++j)
                    acc[i][j] = fmaf(av[i], bv[j], acc[i][j]);
        }
        __syncthreads();
    }
    const int lbase = l0 + ty * 4;
    const int ocbase = oc0 + tx * 4;
    if (oc0 < 256) {
#pragma unroll
        for (int j = 0; j < 4; ++j) {
            int oc = ocbase + j;
            float b = bias[oc];
            float4 v = make_float4((acc[0][j] + b) * SCALE, (acc[1][j] + b) * SCALE,
                                   (acc[2][j] + b) * SCALE, (acc[3][j] + b) * SCALE);
            *(float4*)&qT[oc * L + lbase] = v;
        }
    } else {
        float* dst = (oc0 < 512) ? kpad : vpad;
        const int cb = ocbase - ((oc0 < 512) ? 256 : 512);
#pragma unroll
        for (int i = 0; i < 4; ++i) {
            int l = lbase + i;
            int r = l / HW, s = l % HW;
            int base = (r + 8) * HP + (s + 8);
#pragma unroll
            for (int j = 0; j < 4; ++j)
                dst[(cb + j) * HP2 + base] = acc[i][j] + bias[ocbase + j];
        }
    }
}

// Phase B: logits. Block-uniform (h, n1-chunk); lanes = n. Gather offsets are
// scalar (offtab, uniform index); q in 32 regs reused across the chunk;
// K loads coalesced over consecutive n. P[n1*8+h][n] = <q, K_window>.
__global__ __launch_bounds__(256) void attnB(const float* __restrict__ qT,
                                             const float* __restrict__ kpad,
                                             const int* __restrict__ offtab,
                                             float* __restrict__ P) {
    const int h = blockIdx.y;
    const int n = blockIdx.z * 256 + threadIdx.x;
    const bool valid = (n < L);
    const int nn = valid ? n : 0;
    const int basen = (nn / HW) * HP + (nn % HW);
    float q[32];
#pragma unroll
    for (int k = 0; k < 32; ++k) q[k] = qT[(h * 32 + k) * L + nn];
    const float* kb = kpad + basen;
    int n1 = blockIdx.x * 17;
    for (int b = 0; b < 17; ++b, ++n1) {
        const int j0 = n1 * 256 + h * 32;   // uniform
        float a0 = 0.f, a1 = 0.f, a2 = 0.f, a3 = 0.f;
#pragma unroll
        for (int k = 0; k < 8; ++k) {
            a0 = fmaf(q[k],      kb[offtab[j0 + k]],      a0);
            a1 = fmaf(q[k + 8],  kb[offtab[j0 + k + 8]],  a1);
            a2 = fmaf(q[k + 16], kb[offtab[j0 + k + 16]], a2);
            a3 = fmaf(q[k + 24], kb[offtab[j0 + k + 24]], a3);
        }
        if (valid) P[(n1 * 8 + h) * L + n] = (a0 + a1) + (a2 + a3);
    }
}

// Phase C: per (n, h): max over n1, P := exp(x-max)*mask (UN-normalized),
// inv[h][n] = 1/sum(exp) (sum over ALL slots, pre-mask, as in reference).
__global__ __launch_bounds__(256) void attnC(float* __restrict__ P,
                                             float* __restrict__ inv) {
    __shared__ float red[4][64];
    const int t = threadIdx.x;
    const int h = blockIdx.y;
    const int nl = t & 63;
    const int n = blockIdx.x * 64 + nl;
    const int qtr = t >> 6;
    const int n1lo = qtr * 73;
    const int n1hi = (n1lo + 73 < K2) ? n1lo + 73 : K2;
    const int nr = n / HW, nc = n % HW;
    float mx = -1e30f;
    for (int n1 = n1lo; n1 < n1hi; ++n1)
        mx = fmaxf(mx, P[(n1 * 8 + h) * L + n]);
    red[qtr][nl] = mx;
    __syncthreads();
    mx = fmaxf(fmaxf(red[0][nl], red[1][nl]), fmaxf(red[2][nl], red[3][nl]));
    __syncthreads();
    float s = 0.f;
    for (int n1 = n1lo; n1 < n1hi; ++n1) {
        float v = P[(n1 * 8 + h) * L + n];
        float e = __expf(v - mx);
        s += e;
        int dr = n1 / KW, ds = n1 - dr * KW;       // uniform per iter
        unsigned rr = (unsigned)(nr + dr - 8), ss = (unsigned)(nc + ds - 8);
        float msk = (rr < HW && ss < HW) ? 1.f : 0.f;
        P[(n1 * 8 + h) * L + n] = e * msk;
    }
    red[qtr][nl] = s;
    __syncthreads();
    if (qtr == 0)
        inv[h * L + n] = 1.f / (red[0][nl] + red[1][nl] + red[2][nl] + red[3][nl]);
}

// Phase D: out2T[m][n] = inv[h][n] * sum_n1 P[n1*8+h][n] * V_window.
// Block = 512 thr = 8 waves; wave w owns channel m = bx*8+w (uniform -> scalar
// offtab); lanes = 64 consecutive n. P staged in LDS per 16-n1 tile: each P
// value read once from global per block (4x reuse), broadcast to 8 waves.
__global__ __launch_bounds__(512) void attnD(const float* __restrict__ P,
                                             const float* __restrict__ vpad,
                                             const int* __restrict__ offtab,
                                             const float* __restrict__ inv,
                                             float* __restrict__ outT) {
    __shared__ float Pl[16][64];
    const int tid = threadIdx.x;
    const int w = tid >> 6, nl = tid & 63;
    const int m = blockIdx.x * 8 + w;
    const int h = blockIdx.x >> 2;
    const int n = blockIdx.y * 64 + nl;          // 25*64 = 1600 exactly
    const int basen = (n / HW) * HP + (n % HW);
    const float* vb = vpad + basen;
    float acc = 0.f;
    int n1t = 0;
    for (int t = 0; t < 18; ++t, n1t += 16) {
        __syncthreads();
        Pl[w][nl]     = P[((n1t + w) * 8 + h) * L + n];
        Pl[w + 8][nl] = P[((n1t + w + 8) * 8 + h) * L + n];
        __syncthreads();
#pragma unroll
        for (int r = 0; r < 16; ++r)
            acc = fmaf(Pl[r][nl], vb[offtab[(n1t + r) * 256 + m]], acc);
    }
    // tail n1 = 288
    acc = fmaf(P[(288 * 8 + h) * L + n], vb[offtab[288 * 256 + m]], acc);
    outT[m * L + n] = acc * inv[h * L + n];
}

// out[oc*1600 + l] = sum_c outT[c][l] * w[oc, c] + b[oc]
// (round-4 verified epilogue: acc[i][j] with i = l, j = oc; store 4 l per oc)
__global__ __launch_bounds__(256) void proj_gemm(const float* __restrict__ aT,
                                                 const float* __restrict__ w,
                                                 const float* __restrict__ bias,
                                                 float* __restrict__ out) {
    __shared__ float As[16][68];  // A[c][l]
    __shared__ float Bs[16][68];  // B[c][oc]
    const int l0 = blockIdx.x * 64;
    const int oc0 = blockIdx.y * 64;
    const int tid = threadIdx.x;
    const int tx = tid & 15;   // oc quad
    const int ty = tid >> 4;   // l quad
    float acc[4][4] = {};      // [i: l][j: oc]
    for (int c0 = 0; c0 < C; c0 += 16) {
#pragma unroll
        for (int i = 0; i < 4; ++i) {
            int idx = i * 256 + tid;
            int cc = idx >> 6, ll = idx & 63;
            As[cc][ll] = aT[(c0 + cc) * L + l0 + ll];
        }
#pragma unroll
        for (int i = 0; i < 4; ++i) {
            int idx = i * 256 + tid;
            int cc = idx & 15, oo = idx >> 4;
            Bs[cc][oo] = w[(oc0 + oo) * C + c0 + cc];
        }
        __syncthreads();
#pragma unroll
        for (int kk = 0; kk < 16; ++kk) {
            float4 a = *(const float4*)&As[kk][ty * 4];
            float4 b = *(const float4*)&Bs[kk][tx * 4];
            float av[4] = {a.x, a.y, a.z, a.w};
            float bv[4] = {b.x, b.y, b.z, b.w};
#pragma unroll
            for (int i = 0; i < 4; ++i)
#pragma unroll
                for (int j = 0; j < 4; ++j)
                    acc[i][j] = fmaf(av[i], bv[j], acc[i][j]);
        }
        __syncthreads();
    }
    const int lbase = l0 + ty * 4;
#pragma unroll
    for (int j = 0; j < 4; ++j) {
        int oc = oc0 + tx * 4 + j;
        float bp = bias[oc];
        float4 v = make_float4(acc[0][j] + bp, acc[1][j] + bp,
                               acc[2][j] + bp, acc[3][j] + bp);
        *(float4*)&out[oc * L + lbase] = v;
    }
}

extern "C" void kernel_launch(void* const* d_in, const int* in_sizes, int n_in,
                              void* d_out, int out_size, void* d_ws, size_t ws_size,
                              hipStream_t stream) {
    const float* x      = (const float*)d_in[0];
    const float* w_qkv  = (const float*)d_in[1];
    const float* b_qkv  = (const float*)d_in[2];
    const float* w_proj = (const float*)d_in[3];
    const float* b_proj = (const float*)d_in[4];
    float* out = (float*)d_out;
    float* ws = (float*)d_ws;
    int*   offtab = (int*)(ws + OFF_TAB);
    float* inv  = ws + OFF_INV;
    float* qT   = ws + OFF_QT;   // reused as outT after attnB finishes
    float* kpad = ws + OFF_K;
    float* vpad = ws + OFF_V;
    float* P    = ws + OFF_P;

    // zero padded K/V images (contiguous: 2 * 802816 floats)
    const int n4 = (2 * 802816) / 4;
    zero_kernel<<<n4 / 256, 256, 0, stream>>>((float4*)kpad, n4);
    addr_kernel<<<NJ / 256, 256, 0, stream>>>(offtab);

    qkv_gemm<<<dim3(25, 12), 256, 0, stream>>>(x, w_qkv, b_qkv, qT, kpad, vpad);
    attnB<<<dim3(17, 8, 7), 256, 0, stream>>>(qT, kpad, offtab, P);
    attnC<<<dim3(25, 8), 256, 0, stream>>>(P, inv);
    attnD<<<dim3(32, 25), 512, 0, stream>>>(P, vpad, offtab, inv, qT);
    proj_gemm<<<dim3(25, 4), 256, 0, stream>>>(qT, w_proj, b_proj, out);
}

// Round 8
// 135.671 us; speedup vs baseline: 1.5357x; 1.1646x over previous
//
#include <hip/hip_runtime.h>

#define L 1600
#define C 256
#define HW 40
#define HP 56            // padded spatial (40 + 2*8)
#define HP2 (HP * HP)    // 3136
#define KW 17
#define K2 289
#define HEADS 8
#define SCALE 0.17677669529663687f  // 32^-0.5

// workspace layout (in floats); qT is reused as outT (disjoint lifetimes)
#define OFF_QT 0
#define OFF_K  409600
#define OFF_V  (409600 + 802816)

// qkv[l, oc] = sum_c x[c, l] * w[oc, c] + b[oc]
// q (scaled) -> qT[m][l];  k/v -> padded images
__global__ __launch_bounds__(256) void qkv_gemm(const float* __restrict__ x,
                                                const float* __restrict__ w,
                                                const float* __restrict__ bias,
                                                float* __restrict__ qT,
                                                float* __restrict__ kpad,
                                                float* __restrict__ vpad) {
    __shared__ float As[16][68];  // A[c][l]
    __shared__ float Bs[16][68];  // B[c][oc]
    const int l0 = blockIdx.x * 64;
    const int oc0 = blockIdx.y * 64;
    const int tid = threadIdx.x;
    const int tx = tid & 15;   // oc quad
    const int ty = tid >> 4;   // l quad
    float acc[4][4] = {};
    for (int c0 = 0; c0 < C; c0 += 16) {
#pragma unroll
        for (int i = 0; i < 4; ++i) {
            int idx = i * 256 + tid;
            int cc = idx >> 6, ll = idx & 63;
            As[cc][ll] = x[(c0 + cc) * L + l0 + ll];
        }
#pragma unroll
        for (int i = 0; i < 4; ++i) {
            int idx = i * 256 + tid;
            int cc = idx & 15, oo = idx >> 4;
            Bs[cc][oo] = w[(oc0 + oo) * C + c0 + cc];
        }
        __syncthreads();
#pragma unroll
        for (int kk = 0; kk < 16; ++kk) {
            float4 a = *(const float4*)&As[kk][ty * 4];
            float4 b = *(const float4*)&Bs[kk][tx * 4];
            float av[4] = {a.x, a.y, a.z, a.w};
            float bv[4] = {b.x, b.y, b.z, b.w};
#pragma unroll
            for (int i = 0; i < 4; ++i)
#pragma unroll
                for (int j = 0; j < 4; ++j)
                    acc[i][j] = fmaf(av[i], bv[j], acc[i][j]);
        }
        __syncthreads();
    }
    const int lbase = l0 + ty * 4;
    const int ocbase = oc0 + tx * 4;
    if (oc0 < 256) {
#pragma unroll
        for (int j = 0; j < 4; ++j) {
            int oc = ocbase + j;
            float b = bias[oc];
            float4 v = make_float4((acc[0][j] + b) * SCALE, (acc[1][j] + b) * SCALE,
                                   (acc[2][j] + b) * SCALE, (acc[3][j] + b) * SCALE);
            *(float4*)&qT[oc * L + lbase] = v;
        }
    } else {
        float* dst = (oc0 < 512) ? kpad : vpad;
        const int cb = ocbase - ((oc0 < 512) ? 256 : 512);
#pragma unroll
        for (int i = 0; i < 4; ++i) {
            int l = lbase + i;
            int r = l / HW, s = l % HW;
            int base = (r + 8) * HP + (s + 8);
#pragma unroll
            for (int j = 0; j < 4; ++j)
                dst[(cb + j) * HP2 + base] = acc[i][j] + bias[ocbase + j];
        }
    }
}

// Fused attention: block = (64-n chunk, head). All 289x64 logits live in LDS.
// Scramble bijection: j = n1*256 + h*32 + i  ->  (c, p) = (j/289, j%289);
// offset = c*HP2 + (p/17)*HP + p%17. offh[n1][i] staged in LDS (uniform reads).
__global__ __launch_bounds__(512) void attn_fused(const float* __restrict__ qT,
                                                  const float* __restrict__ kpad,
                                                  const float* __restrict__ vpad,
                                                  float* __restrict__ outT) {
    __shared__ float Plds[K2 * 64];     // 73984 B
    __shared__ int   offh[K2 * 32];     // 36992 B
    __shared__ float red[8 * 64];       // 2048 B
    __shared__ float invl[64];
    const int h = blockIdx.y;
    const int n0 = blockIdx.x * 64;
    const int tid = threadIdx.x;
    const int w = tid >> 6, nl = tid & 63;
    const int n = n0 + nl;
    const int nr = n / HW, nc = n % HW;
    const int basen = nr * HP + nc;
    const float* kb = kpad + basen;
    const float* vb = vpad + basen;

    // stage per-head scrambled offsets
    for (int idx = tid; idx < K2 * 32; idx += 512) {
        int j = (idx >> 5) * 256 + h * 32 + (idx & 31);
        int c = j / K2;
        int p = j - c * K2;
        int dr = p / KW;
        offh[idx] = c * HP2 + dr * HP + (p - dr * KW);
    }
    float q[32];
#pragma unroll
    for (int k = 0; k < 32; ++k) q[k] = qT[(h * 32 + k) * L + n];
    __syncthreads();

    // phase B: logits -> Plds. Wave-uniform n1; lanes = n (coalesced gathers).
    for (int r = 0; r < 37; ++r) {
        int n1 = w + 8 * r;
        if (n1 < K2) {
            const int* ot = offh + n1 * 32;
            float a0 = 0.f, a1 = 0.f, a2 = 0.f, a3 = 0.f;
#pragma unroll
            for (int k = 0; k < 8; ++k) {
                a0 = fmaf(q[k],      kb[ot[k]],      a0);
                a1 = fmaf(q[k + 8],  kb[ot[k + 8]],  a1);
                a2 = fmaf(q[k + 16], kb[ot[k + 16]], a2);
                a3 = fmaf(q[k + 24], kb[ot[k + 24]], a3);
            }
            Plds[n1 * 64 + nl] = (a0 + a1) + (a2 + a3);
        }
    }
    __syncthreads();

    // phase C: per-column (n) softmax over n1; sum pre-mask, mask post (faithful).
    {
        float mx = -1e30f;
        for (int n1 = w; n1 < K2; n1 += 8) mx = fmaxf(mx, Plds[n1 * 64 + nl]);
        red[w * 64 + nl] = mx;
        __syncthreads();
        mx = red[nl];
#pragma unroll
        for (int s2 = 1; s2 < 8; ++s2) mx = fmaxf(mx, red[s2 * 64 + nl]);
        __syncthreads();
        float s = 0.f;
        for (int n1 = w; n1 < K2; n1 += 8) {
            float v = Plds[n1 * 64 + nl];
            float e = __expf(v - mx);
            s += e;
            int dr = n1 / KW, ds = n1 - dr * KW;
            unsigned rr = (unsigned)(nr + dr - 8), ss = (unsigned)(nc + ds - 8);
            float msk = (rr < HW && ss < HW) ? 1.f : 0.f;
            Plds[n1 * 64 + nl] = e * msk;
        }
        red[w * 64 + nl] = s;
        __syncthreads();
        if (w == 0) {
            float t = 0.f;
#pragma unroll
            for (int s2 = 0; s2 < 8; ++s2) t += red[s2 * 64 + nl];
            invl[nl] = 1.f / t;
        }
        __syncthreads();
    }

    // phase D: wave w owns channels mloc = 4w..4w+3; P from LDS broadcast.
    {
        const int mloc = w * 4;
        float acc0 = 0.f, acc1 = 0.f, acc2 = 0.f, acc3 = 0.f;
#pragma unroll 4
        for (int n1 = 0; n1 < K2; ++n1) {
            float p = Plds[n1 * 64 + nl];
            const int* ot = offh + n1 * 32 + mloc;
            acc0 = fmaf(p, vb[ot[0]], acc0);
            acc1 = fmaf(p, vb[ot[1]], acc1);
            acc2 = fmaf(p, vb[ot[2]], acc2);
            acc3 = fmaf(p, vb[ot[3]], acc3);
        }
        const float iv = invl[nl];
        const int m = h * 32 + mloc;
        outT[(m + 0) * L + n] = acc0 * iv;
        outT[(m + 1) * L + n] = acc1 * iv;
        outT[(m + 2) * L + n] = acc2 * iv;
        outT[(m + 3) * L + n] = acc3 * iv;
    }
}

// out[oc*1600 + l] = sum_c outT[c][l] * w[oc, c] + b[oc]
// (round-4 verified epilogue: acc[i][j] with i = l, j = oc; store 4 l per oc)
__global__ __launch_bounds__(256) void proj_gemm(const float* __restrict__ aT,
                                                 const float* __restrict__ w,
                                                 const float* __restrict__ bias,
                                                 float* __restrict__ out) {
    __shared__ float As[16][68];  // A[c][l]
    __shared__ float Bs[16][68];  // B[c][oc]
    const int l0 = blockIdx.x * 64;
    const int oc0 = blockIdx.y * 64;
    const int tid = threadIdx.x;
    const int tx = tid & 15;   // oc quad
    const int ty = tid >> 4;   // l quad
    float acc[4][4] = {};      // [i: l][j: oc]
    for (int c0 = 0; c0 < C; c0 += 16) {
#pragma unroll
        for (int i = 0; i < 4; ++i) {
            int idx = i * 256 + tid;
            int cc = idx >> 6, ll = idx & 63;
            As[cc][ll] = aT[(c0 + cc) * L + l0 + ll];
        }
#pragma unroll
        for (int i = 0; i < 4; ++i) {
            int idx = i * 256 + tid;
            int cc = idx & 15, oo = idx >> 4;
            Bs[cc][oo] = w[(oc0 + oo) * C + c0 + cc];
        }
        __syncthreads();
#pragma unroll
        for (int kk = 0; kk < 16; ++kk) {
            float4 a = *(const float4*)&As[kk][ty * 4];
            float4 b = *(const float4*)&Bs[kk][tx * 4];
            float av[4] = {a.x, a.y, a.z, a.w};
            float bv[4] = {b.x, b.y, b.z, b.w};
#pragma unroll
            for (int i = 0; i < 4; ++i)
#pragma unroll
                for (int j = 0; j < 4; ++j)
                    acc[i][j] = fmaf(av[i], bv[j], acc[i][j]);
        }
        __syncthreads();
    }
    const int lbase = l0 + ty * 4;
#pragma unroll
    for (int j = 0; j < 4; ++j) {
        int oc = oc0 + tx * 4 + j;
        float bp = bias[oc];
        float4 v = make_float4(acc[0][j] + bp, acc[1][j] + bp,
                               acc[2][j] + bp, acc[3][j] + bp);
        *(float4*)&out[oc * L + lbase] = v;
    }
}

extern "C" void kernel_launch(void* const* d_in, const int* in_sizes, int n_in,
                              void* d_out, int out_size, void* d_ws, size_t ws_size,
                              hipStream_t stream) {
    const float* x      = (const float*)d_in[0];
    const float* w_qkv  = (const float*)d_in[1];
    const float* b_qkv  = (const float*)d_in[2];
    const float* w_proj = (const float*)d_in[3];
    const float* b_proj = (const float*)d_in[4];
    float* out = (float*)d_out;
    float* ws = (float*)d_ws;
    float* qT   = ws + OFF_QT;   // reused as outT (disjoint lifetimes)
    float* kpad = ws + OFF_K;
    float* vpad = ws + OFF_V;

    // zero padded K/V images (contiguous: 2 * 802816 floats)
    hipMemsetAsync(kpad, 0, (size_t)2 * 802816 * sizeof(float), stream);

    qkv_gemm<<<dim3(25, 12), 256, 0, stream>>>(x, w_qkv, b_qkv, qT, kpad, vpad);
    attn_fused<<<dim3(25, 8), 512, 0, stream>>>(qT, kpad, vpad, qT);
    proj_gemm<<<dim3(25, 4), 256, 0, stream>>>(qT, w_proj, b_proj, out);
}

// Round 9
// 135.631 us; speedup vs baseline: 1.5362x; 1.0003x over previous
//
#include <hip/hip_runtime.h>

#define L 1600
#define C 256
#define HW 40
#define HP 56            // padded spatial (40 + 2*8)
#define HP2 (HP * HP)    // 3136
#define KW 17
#define K2 289
#define HEADS 8
#define NT 16            // n-columns per attn block
#define SCALE 0.17677669529663687f  // 32^-0.5

// workspace layout (in floats); qT is reused as outT (disjoint lifetimes)
#define OFF_TABH 0                      // 8 * 289 * 32 ints = 73984
#define OFF_QT   73984
#define OFF_K    (73984 + 409600)
#define OFF_V    (73984 + 409600 + 802816)

// offtabH[h][n1][i] = padded-image offset of flat-window element j = n1*256+h*32+i
__global__ __launch_bounds__(256) void addr_kernel(int* __restrict__ offtabH) {
    int idx = blockIdx.x * 256 + threadIdx.x;   // grid = 289*256 = 8*9248 exactly
    int h = idx / 9248;
    int rem = idx - h * 9248;
    int n1 = rem >> 5, i = rem & 31;
    int j = n1 * 256 + h * 32 + i;
    int c = j / K2;
    int p = j - c * K2;
    int dr = p / KW;
    offtabH[idx] = c * HP2 + dr * HP + (p - dr * KW);
}

// qkv[l, oc] = sum_c x[c, l] * w[oc, c] + b[oc]
// q (scaled) -> qT[m][l];  k/v -> padded images    (verified r4-r8)
__global__ __launch_bounds__(256) void qkv_gemm(const float* __restrict__ x,
                                                const float* __restrict__ w,
                                                const float* __restrict__ bias,
                                                float* __restrict__ qT,
                                                float* __restrict__ kpad,
                                                float* __restrict__ vpad) {
    __shared__ float As[16][68];  // A[c][l]
    __shared__ float Bs[16][68];  // B[c][oc]
    const int l0 = blockIdx.x * 64;
    const int oc0 = blockIdx.y * 64;
    const int tid = threadIdx.x;
    const int tx = tid & 15;   // oc quad
    const int ty = tid >> 4;   // l quad
    float acc[4][4] = {};
    for (int c0 = 0; c0 < C; c0 += 16) {
#pragma unroll
        for (int i = 0; i < 4; ++i) {
            int idx = i * 256 + tid;
            int cc = idx >> 6, ll = idx & 63;
            As[cc][ll] = x[(c0 + cc) * L + l0 + ll];
        }
#pragma unroll
        for (int i = 0; i < 4; ++i) {
            int idx = i * 256 + tid;
            int cc = idx & 15, oo = idx >> 4;
            Bs[cc][oo] = w[(oc0 + oo) * C + c0 + cc];
        }
        __syncthreads();
#pragma unroll
        for (int kk = 0; kk < 16; ++kk) {
            float4 a = *(const float4*)&As[kk][ty * 4];
            float4 b = *(const float4*)&Bs[kk][tx * 4];
            float av[4] = {a.x, a.y, a.z, a.w};
            float bv[4] = {b.x, b.y, b.z, b.w};
#pragma unroll
            for (int i = 0; i < 4; ++i)
#pragma unroll
                for (int j = 0; j < 4; ++j)
                    acc[i][j] = fmaf(av[i], bv[j], acc[i][j]);
        }
        __syncthreads();
    }
    const int lbase = l0 + ty * 4;
    const int ocbase = oc0 + tx * 4;
    if (oc0 < 256) {
#pragma unroll
        for (int j = 0; j < 4; ++j) {
            int oc = ocbase + j;
            float b = bias[oc];
            float4 v = make_float4((acc[0][j] + b) * SCALE, (acc[1][j] + b) * SCALE,
                                   (acc[2][j] + b) * SCALE, (acc[3][j] + b) * SCALE);
            *(float4*)&qT[oc * L + lbase] = v;
        }
    } else {
        float* dst = (oc0 < 512) ? kpad : vpad;
        const int cb = ocbase - ((oc0 < 512) ? 256 : 512);
#pragma unroll
        for (int i = 0; i < 4; ++i) {
            int l = lbase + i;
            int r = l / HW, s = l % HW;
            int base = (r + 8) * HP + (s + 8);
#pragma unroll
            for (int j = 0; j < 4; ++j)
                dst[(cb + j) * HP2 + base] = acc[i][j] + bias[ocbase + j];
        }
    }
}

// Fused attention, 16 n-columns per block. Block (bx: n-chunk, by: head).
// Lanes: nn = nl&15 (n column), q4 = nl>>4 (n1 sub-slot). Offsets read as int4
// from global offtabH (uniform per quarter, L2-resident). Logits live in LDS.
__global__ __launch_bounds__(512) void attn_fused(const float* __restrict__ qT,
                                                  const float* __restrict__ kpad,
                                                  const float* __restrict__ vpad,
                                                  const int* __restrict__ offtabH,
                                                  float* __restrict__ outT) {
    __shared__ float Plds[K2 * NT];     // 18496 B
    __shared__ float red[32 * NT];      // 2048 B
    __shared__ float colmax[NT], invl[NT];
    const int h = blockIdx.y;
    const int n0 = blockIdx.x * NT;
    const int tid = threadIdx.x;
    const int w = tid >> 6, nl = tid & 63;
    const int q4 = nl >> 4, nn = nl & 15;
    const int n = n0 + nn;
    const int basen = (n / HW) * HP + (n % HW);
    const float* kb = kpad + basen;
    const float* vb = vpad + basen;
    const int4* otH = (const int4*)(offtabH + h * (K2 * 32));  // [n1*8 + k4]

    float qreg[32];
#pragma unroll
    for (int k = 0; k < 32; ++k) qreg[k] = qT[(h * 32 + k) * L + n];

    // phase B: logits. Round r: wave w, quarter q4 -> n1 = 32r + 4w + q4.
#pragma unroll 3
    for (int r = 0; r < 9; ++r) {
        const int n1 = r * 32 + w * 4 + q4;
        float a0 = 0.f, a1 = 0.f, a2 = 0.f, a3 = 0.f;
#pragma unroll
        for (int k4 = 0; k4 < 8; ++k4) {
            int4 o = otH[n1 * 8 + k4];
            a0 = fmaf(qreg[k4 * 4 + 0], kb[o.x], a0);
            a1 = fmaf(qreg[k4 * 4 + 1], kb[o.y], a1);
            a2 = fmaf(qreg[k4 * 4 + 2], kb[o.z], a2);
            a3 = fmaf(qreg[k4 * 4 + 3], kb[o.w], a3);
        }
        Plds[n1 * NT + nn] = (a0 + a1) + (a2 + a3);
    }
    if (w * 4 + q4 == 0) {  // tail n1 = 288 (lanes 0-15 of wave 0)
        float a0 = 0.f, a1 = 0.f, a2 = 0.f, a3 = 0.f;
#pragma unroll
        for (int k4 = 0; k4 < 8; ++k4) {
            int4 o = otH[288 * 8 + k4];
            a0 = fmaf(qreg[k4 * 4 + 0], kb[o.x], a0);
            a1 = fmaf(qreg[k4 * 4 + 1], kb[o.y], a1);
            a2 = fmaf(qreg[k4 * 4 + 2], kb[o.z], a2);
            a3 = fmaf(qreg[k4 * 4 + 3], kb[o.w], a3);
        }
        Plds[288 * NT + nn] = (a0 + a1) + (a2 + a3);
    }
    __syncthreads();

    // phase C: per-column softmax over n1; sum pre-mask, mask post (faithful).
    {
        const int col = tid & 15, seg = tid >> 4;
        float mx = -1e30f;
        for (int n1 = seg; n1 < K2; n1 += 32) mx = fmaxf(mx, Plds[n1 * NT + col]);
        red[seg * NT + col] = mx;
        __syncthreads();
        if (tid < NT) {
            float m = red[tid];
            for (int s = 1; s < 32; ++s) m = fmaxf(m, red[s * NT + tid]);
            colmax[tid] = m;
        }
        __syncthreads();
        const int ncn = n0 + col;
        const int nr = ncn / HW, nc = ncn % HW;
        const float mxc = colmax[col];
        float s = 0.f;
        for (int n1 = seg; n1 < K2; n1 += 32) {
            float e = __expf(Plds[n1 * NT + col] - mxc);
            s += e;
            int dr = n1 / KW, ds = n1 - dr * KW;
            unsigned rr = (unsigned)(nr + dr - 8), ss = (unsigned)(nc + ds - 8);
            Plds[n1 * NT + col] = (rr < HW && ss < HW) ? e : 0.f;
        }
        red[seg * NT + col] = s;
        __syncthreads();
        if (tid < NT) {
            float t = 0.f;
            for (int s2 = 0; s2 < 32; ++s2) t += red[s2 * NT + tid];
            invl[tid] = 1.f / t;
        }
        __syncthreads();
    }

    // phase D: wave w owns channels h*32 + 4w .. +3; lane quarter q4 covers
    // n1 = 4t + q4; cross-quarter shfl reduce at the end.
    {
        float a0 = 0.f, a1 = 0.f, a2 = 0.f, a3 = 0.f;
#pragma unroll 4
        for (int t = 0; t < 72; ++t) {
            const int n1 = t * 4 + q4;
            const float p = Plds[n1 * NT + nn];
            int4 o = otH[n1 * 8 + w];
            a0 = fmaf(p, vb[o.x], a0);
            a1 = fmaf(p, vb[o.y], a1);
            a2 = fmaf(p, vb[o.z], a2);
            a3 = fmaf(p, vb[o.w], a3);
        }
        if (q4 == 0) {  // tail n1 = 288
            const float p = Plds[288 * NT + nn];
            int4 o = otH[288 * 8 + w];
            a0 = fmaf(p, vb[o.x], a0);
            a1 = fmaf(p, vb[o.y], a1);
            a2 = fmaf(p, vb[o.z], a2);
            a3 = fmaf(p, vb[o.w], a3);
        }
        a0 += __shfl_xor(a0, 16, 64); a0 += __shfl_xor(a0, 32, 64);
        a1 += __shfl_xor(a1, 16, 64); a1 += __shfl_xor(a1, 32, 64);
        a2 += __shfl_xor(a2, 16, 64); a2 += __shfl_xor(a2, 32, 64);
        a3 += __shfl_xor(a3, 16, 64); a3 += __shfl_xor(a3, 32, 64);
        if (q4 == 0) {
            const float iv = invl[nn];
            const int m = h * 32 + w * 4;
            outT[(m + 0) * L + n] = a0 * iv;
            outT[(m + 1) * L + n] = a1 * iv;
            outT[(m + 2) * L + n] = a2 * iv;
            outT[(m + 3) * L + n] = a3 * iv;
        }
    }
}

// out[oc*1600 + l] = sum_c outT[c][l] * w[oc, c] + b[oc]   (verified r4/r7/r8)
__global__ __launch_bounds__(256) void proj_gemm(const float* __restrict__ aT,
                                                 const float* __restrict__ w,
                                                 const float* __restrict__ bias,
                                                 float* __restrict__ out) {
    __shared__ float As[16][68];  // A[c][l]
    __shared__ float Bs[16][68];  // B[c][oc]
    const int l0 = blockIdx.x * 64;
    const int oc0 = blockIdx.y * 64;
    const int tid = threadIdx.x;
    const int tx = tid & 15;   // oc quad
    const int ty = tid >> 4;   // l quad
    float acc[4][4] = {};      // [i: l][j: oc]
    for (int c0 = 0; c0 < C; c0 += 16) {
#pragma unroll
        for (int i = 0; i < 4; ++i) {
            int idx = i * 256 + tid;
            int cc = idx >> 6, ll = idx & 63;
            As[cc][ll] = aT[(c0 + cc) * L + l0 + ll];
        }
#pragma unroll
        for (int i = 0; i < 4; ++i) {
            int idx = i * 256 + tid;
            int cc = idx & 15, oo = idx >> 4;
            Bs[cc][oo] = w[(oc0 + oo) * C + c0 + cc];
        }
        __syncthreads();
#pragma unroll
        for (int kk = 0; kk < 16; ++kk) {
            float4 a = *(const float4*)&As[kk][ty * 4];
            float4 b = *(const float4*)&Bs[kk][tx * 4];
            float av[4] = {a.x, a.y, a.z, a.w};
            float bv[4] = {b.x, b.y, b.z, b.w};
#pragma unroll
            for (int i = 0; i < 4; ++i)
#pragma unroll
                for (int j = 0; j < 4; ++j)
                    acc[i][j] = fmaf(av[i], bv[j], acc[i][j]);
        }
        __syncthreads();
    }
    const int lbase = l0 + ty * 4;
#pragma unroll
    for (int j = 0; j < 4; ++j) {
        int oc = oc0 + tx * 4 + j;
        float bp = bias[oc];
        float4 v = make_float4(acc[0][j] + bp, acc[1][j] + bp,
                               acc[2][j] + bp, acc[3][j] + bp);
        *(float4*)&out[oc * L + lbase] = v;
    }
}

extern "C" void kernel_launch(void* const* d_in, const int* in_sizes, int n_in,
                              void* d_out, int out_size, void* d_ws, size_t ws_size,
                              hipStream_t stream) {
    const float* x      = (const float*)d_in[0];
    const float* w_qkv  = (const float*)d_in[1];
    const float* b_qkv  = (const float*)d_in[2];
    const float* w_proj = (const float*)d_in[3];
    const float* b_proj = (const float*)d_in[4];
    float* out = (float*)d_out;
    float* ws = (float*)d_ws;
    int*   offtabH = (int*)(ws + OFF_TABH);
    float* qT   = ws + OFF_QT;   // reused as outT (disjoint lifetimes)
    float* kpad = ws + OFF_K;
    float* vpad = ws + OFF_V;

    // zero padded K/V images (contiguous: 2 * 802816 floats)
    hipMemsetAsync(kpad, 0, (size_t)2 * 802816 * sizeof(float), stream);
    addr_kernel<<<289, 256, 0, stream>>>(offtabH);

    qkv_gemm<<<dim3(25, 12), 256, 0, stream>>>(x, w_qkv, b_qkv, qT, kpad, vpad);
    attn_fused<<<dim3(100, 8), 512, 0, stream>>>(qT, kpad, vpad, offtabH, qT);
    proj_gemm<<<dim3(25, 4), 256, 0, stream>>>(qT, w_proj, b_proj, out);
}

// Round 10
// 133.221 us; speedup vs baseline: 1.5640x; 1.0181x over previous
//
#include <hip/hip_runtime.h>

#define L 1600
#define C 256
#define HW 40
#define HP 56            // padded spatial (40 + 2*8)
#define HP2 (HP * HP)    // 3136
#define KW 17
#define K2 289
#define HEADS 8
#define NT 16            // n-columns per attn block
#define SCALE 0.17677669529663687f  // 32^-0.5

// workspace layout (in floats); qT is reused as outT (disjoint lifetimes)
#define OFF_TABH 0                      // 8 * 289 * 32 ints = 73984
#define OFF_QT   73984
#define OFF_K    (73984 + 409600)
#define OFF_V    (73984 + 409600 + 802816)

// offtabH[h][n1][i] = padded-image offset of flat-window element j = n1*256+h*32+i
__global__ __launch_bounds__(256) void addr_kernel(int* __restrict__ offtabH) {
    int idx = blockIdx.x * 256 + threadIdx.x;   // grid = 289*256 = 8*9248 exactly
    int h = idx / 9248;
    int rem = idx - h * 9248;
    int n1 = rem >> 5, i = rem & 31;
    int j = n1 * 256 + h * 32 + i;
    int c = j / K2;
    int p = j - c * K2;
    int dr = p / KW;
    offtabH[idx] = c * HP2 + dr * HP + (p - dr * KW);
}

// qkv[l, oc] = sum_c x[c, l] * w[oc, c] + b[oc]
// q (scaled) -> qT[m][l];  k/v -> padded images    (verified r4-r9)
__global__ __launch_bounds__(256) void qkv_gemm(const float* __restrict__ x,
                                                const float* __restrict__ w,
                                                const float* __restrict__ bias,
                                                float* __restrict__ qT,
                                                float* __restrict__ kpad,
                                                float* __restrict__ vpad) {
    __shared__ float As[16][68];  // A[c][l]
    __shared__ float Bs[16][68];  // B[c][oc]
    const int l0 = blockIdx.x * 64;
    const int oc0 = blockIdx.y * 64;
    const int tid = threadIdx.x;
    const int tx = tid & 15;   // oc quad
    const int ty = tid >> 4;   // l quad
    float acc[4][4] = {};
    for (int c0 = 0; c0 < C; c0 += 16) {
#pragma unroll
        for (int i = 0; i < 4; ++i) {
            int idx = i * 256 + tid;
            int cc = idx >> 6, ll = idx & 63;
            As[cc][ll] = x[(c0 + cc) * L + l0 + ll];
        }
#pragma unroll
        for (int i = 0; i < 4; ++i) {
            int idx = i * 256 + tid;
            int cc = idx & 15, oo = idx >> 4;
            Bs[cc][oo] = w[(oc0 + oo) * C + c0 + cc];
        }
        __syncthreads();
#pragma unroll
        for (int kk = 0; kk < 16; ++kk) {
            float4 a = *(const float4*)&As[kk][ty * 4];
            float4 b = *(const float4*)&Bs[kk][tx * 4];
            float av[4] = {a.x, a.y, a.z, a.w};
            float bv[4] = {b.x, b.y, b.z, b.w};
#pragma unroll
            for (int i = 0; i < 4; ++i)
#pragma unroll
                for (int j = 0; j < 4; ++j)
                    acc[i][j] = fmaf(av[i], bv[j], acc[i][j]);
        }
        __syncthreads();
    }
    const int lbase = l0 + ty * 4;
    const int ocbase = oc0 + tx * 4;
    if (oc0 < 256) {
#pragma unroll
        for (int j = 0; j < 4; ++j) {
            int oc = ocbase + j;
            float b = bias[oc];
            float4 v = make_float4((acc[0][j] + b) * SCALE, (acc[1][j] + b) * SCALE,
                                   (acc[2][j] + b) * SCALE, (acc[3][j] + b) * SCALE);
            *(float4*)&qT[oc * L + lbase] = v;
        }
    } else {
        float* dst = (oc0 < 512) ? kpad : vpad;
        const int cb = ocbase - ((oc0 < 512) ? 256 : 512);
#pragma unroll
        for (int i = 0; i < 4; ++i) {
            int l = lbase + i;
            int r = l / HW, s = l % HW;
            int base = (r + 8) * HP + (s + 8);
#pragma unroll
            for (int j = 0; j < 4; ++j)
                dst[(cb + j) * HP2 + base] = acc[i][j] + bias[ocbase + j];
        }
    }
}

// Fused attention, 16 n-columns per block. Flat grid 800 with bijective XCD
// swizzle: wgid = (bid%8)*100 + bid/8; h = wgid%8, nchunk = wgid/8 -> each XCD
// gets ~13 contiguous n-chunks x all heads (K/V slab ~2.6 MB < 4 MB L2).
__global__ __launch_bounds__(512) void attn_fused(const float* __restrict__ qT,
                                                  const float* __restrict__ kpad,
                                                  const float* __restrict__ vpad,
                                                  const int* __restrict__ offtabH,
                                                  float* __restrict__ outT) {
    __shared__ float Plds[K2 * NT];     // 18496 B
    __shared__ float red[32 * NT];      // 2048 B
    __shared__ float colmax[NT], invl[NT];
    const int bid = blockIdx.x;
    const int wgid = (bid & 7) * 100 + (bid >> 3);
    const int h = wgid & 7;
    const int n0 = (wgid >> 3) * NT;
    const int tid = threadIdx.x;
    const int w = tid >> 6, nl = tid & 63;
    const int q4 = nl >> 4, nn = nl & 15;
    const int n = n0 + nn;
    const int basen = (n / HW) * HP + (n % HW);
    const float* kb = kpad + basen;
    const float* vb = vpad + basen;
    const int* otF = offtabH + h * (K2 * 32);
    const int4* otH = (const int4*)otF;           // [n1*8 + k4]

    float qreg[32];
#pragma unroll
    for (int k = 0; k < 32; ++k) qreg[k] = qT[(h * 32 + k) * L + n];

    // phase B: logits. Round r: wave w, quarter q4 -> n1 = 32r + 4w + q4.
#pragma unroll 3
    for (int r = 0; r < 9; ++r) {
        const int n1 = r * 32 + w * 4 + q4;
        float a0 = 0.f, a1 = 0.f, a2 = 0.f, a3 = 0.f;
#pragma unroll
        for (int k4 = 0; k4 < 8; ++k4) {
            int4 o = otH[n1 * 8 + k4];
            a0 = fmaf(qreg[k4 * 4 + 0], kb[o.x], a0);
            a1 = fmaf(qreg[k4 * 4 + 1], kb[o.y], a1);
            a2 = fmaf(qreg[k4 * 4 + 2], kb[o.z], a2);
            a3 = fmaf(qreg[k4 * 4 + 3], kb[o.w], a3);
        }
        Plds[n1 * NT + nn] = (a0 + a1) + (a2 + a3);
    }
    if (w * 4 + q4 == 0) {  // tail n1 = 288 (lanes 0-15 of wave 0)
        float a0 = 0.f, a1 = 0.f, a2 = 0.f, a3 = 0.f;
#pragma unroll
        for (int k4 = 0; k4 < 8; ++k4) {
            int4 o = otH[288 * 8 + k4];
            a0 = fmaf(qreg[k4 * 4 + 0], kb[o.x], a0);
            a1 = fmaf(qreg[k4 * 4 + 1], kb[o.y], a1);
            a2 = fmaf(qreg[k4 * 4 + 2], kb[o.z], a2);
            a3 = fmaf(qreg[k4 * 4 + 3], kb[o.w], a3);
        }
        Plds[288 * NT + nn] = (a0 + a1) + (a2 + a3);
    }
    __syncthreads();

    // phase C: per-column softmax over n1; sum pre-mask, mask post (faithful).
    {
        const int col = tid & 15, seg = tid >> 4;
        float mx = -1e30f;
        for (int n1 = seg; n1 < K2; n1 += 32) mx = fmaxf(mx, Plds[n1 * NT + col]);
        red[seg * NT + col] = mx;
        __syncthreads();
        if (tid < NT) {
            float m = red[tid];
            for (int s = 1; s < 32; ++s) m = fmaxf(m, red[s * NT + tid]);
            colmax[tid] = m;
        }
        __syncthreads();
        const int ncn = n0 + col;
        const int nr = ncn / HW, nc = ncn % HW;
        const float mxc = colmax[col];
        float s = 0.f;
        for (int n1 = seg; n1 < K2; n1 += 32) {
            float e = __expf(Plds[n1 * NT + col] - mxc);
            s += e;
            int dr = n1 / KW, ds = n1 - dr * KW;
            unsigned rr = (unsigned)(nr + dr - 8), ss = (unsigned)(nc + ds - 8);
            Plds[n1 * NT + col] = (rr < HW && ss < HW) ? e : 0.f;
        }
        red[seg * NT + col] = s;
        __syncthreads();
        if (tid < NT) {
            float t = 0.f;
            for (int s2 = 0; s2 < 32; ++s2) t += red[s2 * NT + tid];
            invl[tid] = 1.f / t;
        }
        __syncthreads();
    }

    // phase D: lane = (channel mq = w*4+q4, column nn). n1 wave-uniform ->
    // P reads are LDS broadcasts; V gathers 4 ch x 16 consecutive n; no shuffles.
    {
        const int mq = w * 4 + q4;
        float a0 = 0.f, a1 = 0.f, a2 = 0.f, a3 = 0.f;
#pragma unroll 4
        for (int t = 0; t < 72; ++t) {
            const int n1 = t * 4;
            float p0 = Plds[(n1 + 0) * NT + nn];
            float p1 = Plds[(n1 + 1) * NT + nn];
            float p2 = Plds[(n1 + 2) * NT + nn];
            float p3 = Plds[(n1 + 3) * NT + nn];
            a0 = fmaf(p0, vb[otF[(n1 + 0) * 32 + mq]], a0);
            a1 = fmaf(p1, vb[otF[(n1 + 1) * 32 + mq]], a1);
            a2 = fmaf(p2, vb[otF[(n1 + 2) * 32 + mq]], a2);
            a3 = fmaf(p3, vb[otF[(n1 + 3) * 32 + mq]], a3);
        }
        a0 = fmaf(Plds[288 * NT + nn], vb[otF[288 * 32 + mq]], a0);
        const float acc = (a0 + a1) + (a2 + a3);
        outT[(h * 32 + mq) * L + n] = acc * invl[nn];
    }
}

// out[oc*1600 + l] = sum_c outT[c][l] * w[oc, c] + b[oc]   (verified r4/r7-r9)
__global__ __launch_bounds__(256) void proj_gemm(const float* __restrict__ aT,
                                                 const float* __restrict__ w,
                                                 const float* __restrict__ bias,
                                                 float* __restrict__ out) {
    __shared__ float As[16][68];  // A[c][l]
    __shared__ float Bs[16][68];  // B[c][oc]
    const int l0 = blockIdx.x * 64;
    const int oc0 = blockIdx.y * 64;
    const int tid = threadIdx.x;
    const int tx = tid & 15;   // oc quad
    const int ty = tid >> 4;   // l quad
    float acc[4][4] = {};      // [i: l][j: oc]
    for (int c0 = 0; c0 < C; c0 += 16) {
#pragma unroll
        for (int i = 0; i < 4; ++i) {
            int idx = i * 256 + tid;
            int cc = idx >> 6, ll = idx & 63;
            As[cc][ll] = aT[(c0 + cc) * L + l0 + ll];
        }
#pragma unroll
        for (int i = 0; i < 4; ++i) {
            int idx = i * 256 + tid;
            int cc = idx & 15, oo = idx >> 4;
            Bs[cc][oo] = w[(oc0 + oo) * C + c0 + cc];
        }
        __syncthreads();
#pragma unroll
        for (int kk = 0; kk < 16; ++kk) {
            float4 a = *(const float4*)&As[kk][ty * 4];
            float4 b = *(const float4*)&Bs[kk][tx * 4];
            float av[4] = {a.x, a.y, a.z, a.w};
            float bv[4] = {b.x, b.y, b.z, b.w};
#pragma unroll
            for (int i = 0; i < 4; ++i)
#pragma unroll
                for (int j = 0; j < 4; ++j)
                    acc[i][j] = fmaf(av[i], bv[j], acc[i][j]);
        }
        __syncthreads();
    }
    const int lbase = l0 + ty * 4;
#pragma unroll
    for (int j = 0; j < 4; ++j) {
        int oc = oc0 + tx * 4 + j;
        float bp = bias[oc];
        float4 v = make_float4(acc[0][j] + bp, acc[1][j] + bp,
                               acc[2][j] + bp, acc[3][j] + bp);
        *(float4*)&out[oc * L + lbase] = v;
    }
}

extern "C" void kernel_launch(void* const* d_in, const int* in_sizes, int n_in,
                              void* d_out, int out_size, void* d_ws, size_t ws_size,
                              hipStream_t stream) {
    const float* x      = (const float*)d_in[0];
    const float* w_qkv  = (const float*)d_in[1];
    const float* b_qkv  = (const float*)d_in[2];
    const float* w_proj = (const float*)d_in[3];
    const float* b_proj = (const float*)d_in[4];
    float* out = (float*)d_out;
    float* ws = (float*)d_ws;
    int*   offtabH = (int*)(ws + OFF_TABH);
    float* qT   = ws + OFF_QT;   // reused as outT (disjoint lifetimes)
    float* kpad = ws + OFF_K;
    float* vpad = ws + OFF_V;

    // zero padded K/V images (contiguous: 2 * 802816 floats)
    hipMemsetAsync(kpad, 0, (size_t)2 * 802816 * sizeof(float), stream);
    addr_kernel<<<289, 256, 0, stream>>>(offtabH);

    qkv_gemm<<<dim3(25, 12), 256, 0, stream>>>(x, w_qkv, b_qkv, qT, kpad, vpad);
    attn_fused<<<800, 512, 0, stream>>>(qT, kpad, vpad, offtabH, qT);
    proj_gemm<<<dim3(25, 4), 256, 0, stream>>>(qT, w_proj, b_proj, out);
}

// Round 11
// 124.691 us; speedup vs baseline: 1.6709x; 1.0684x over previous
//
#include <hip/hip_runtime.h>
#include <hip/hip_fp16.h>

#define L 1600
#define C 256
#define HW 40
#define HP 56            // padded spatial (40 + 2*8)
#define HP2 (HP * HP)    // 3136
#define KW 17
#define K2 289
#define HEADS 8
#define NT 16            // n-columns per attn block
#define K2P 292          // K2 padded to multiple of 4 (int4 loads)
#define SCALE 0.17677669529663687f  // 32^-0.5

// workspace layout (float slots); qT reused as outT (disjoint lifetimes)
#define OFF_TH 0                         // otH: 8*289*32 ints   = 73984
#define OFF_TD 73984                     // otD: 8*32*292 ints   = 74752
#define OFF_QT 148736                    // qT/outT: 409600 f
#define OFF_KH 558336                    // kpadH: 802816 halves = 401408 slots
#define OFF_VH 959744                    // vpadH: 802816 halves

// otH[h][n1][i] = image offset of flat-window element j = n1*256+h*32+i
// otD[h][i][n1] = same value, transposed for phase D (padded n1 to 292)
__global__ __launch_bounds__(256) void addr_kernel(int* __restrict__ otH,
                                                   int* __restrict__ otD) {
    int idx = blockIdx.x * 256 + threadIdx.x;   // grid = 8*292*32/256 = 292 blocks
    int h = idx / (K2P * 32);
    int rem = idx - h * (K2P * 32);
    int n1 = rem >> 5, i = rem & 31;
    int off = 0;
    if (n1 < K2) {
        int j = n1 * 256 + h * 32 + i;
        int c = j / K2;
        int p = j - c * K2;
        int dr = p / KW;
        off = c * HP2 + dr * HP + (p - dr * KW);
        otH[(h * K2 + n1) * 32 + i] = off;
    }
    otD[(h * 32 + i) * K2P + n1] = off;
}

// qkv[l, oc] = sum_c x[c, l] * w[oc, c] + b[oc]
// q (scaled) -> qT[m][l] f32;  k/v -> fp16 padded images   (structure verified r4-r10)
__global__ __launch_bounds__(256) void qkv_gemm(const float* __restrict__ x,
                                                const float* __restrict__ w,
                                                const float* __restrict__ bias,
                                                float* __restrict__ qT,
                                                __half* __restrict__ kpadH,
                                                __half* __restrict__ vpadH) {
    __shared__ float As[16][68];  // A[c][l]
    __shared__ float Bs[16][68];  // B[c][oc]
    const int l0 = blockIdx.x * 64;
    const int oc0 = blockIdx.y * 64;
    const int tid = threadIdx.x;
    const int tx = tid & 15;   // oc quad
    const int ty = tid >> 4;   // l quad
    float acc[4][4] = {};
    for (int c0 = 0; c0 < C; c0 += 16) {
#pragma unroll
        for (int i = 0; i < 4; ++i) {
            int idx = i * 256 + tid;
            int cc = idx >> 6, ll = idx & 63;
            As[cc][ll] = x[(c0 + cc) * L + l0 + ll];
        }
#pragma unroll
        for (int i = 0; i < 4; ++i) {
            int idx = i * 256 + tid;
            int cc = idx & 15, oo = idx >> 4;
            Bs[cc][oo] = w[(oc0 + oo) * C + c0 + cc];
        }
        __syncthreads();
#pragma unroll
        for (int kk = 0; kk < 16; ++kk) {
            float4 a = *(const float4*)&As[kk][ty * 4];
            float4 b = *(const float4*)&Bs[kk][tx * 4];
            float av[4] = {a.x, a.y, a.z, a.w};
            float bv[4] = {b.x, b.y, b.z, b.w};
#pragma unroll
            for (int i = 0; i < 4; ++i)
#pragma unroll
                for (int j = 0; j < 4; ++j)
                    acc[i][j] = fmaf(av[i], bv[j], acc[i][j]);
        }
        __syncthreads();
    }
    const int lbase = l0 + ty * 4;
    const int ocbase = oc0 + tx * 4;
    if (oc0 < 256) {
#pragma unroll
        for (int j = 0; j < 4; ++j) {
            int oc = ocbase + j;
            float b = bias[oc];
            float4 v = make_float4((acc[0][j] + b) * SCALE, (acc[1][j] + b) * SCALE,
                                   (acc[2][j] + b) * SCALE, (acc[3][j] + b) * SCALE);
            *(float4*)&qT[oc * L + lbase] = v;
        }
    } else {
        __half* dst = (oc0 < 512) ? kpadH : vpadH;
        const int cb = ocbase - ((oc0 < 512) ? 256 : 512);
#pragma unroll
        for (int i = 0; i < 4; ++i) {
            int l = lbase + i;
            int r = l / HW, s = l % HW;
            int base = (r + 8) * HP + (s + 8);
#pragma unroll
            for (int j = 0; j < 4; ++j)
                dst[(cb + j) * HP2 + base] = __float2half(acc[i][j] + bias[ocbase + j]);
        }
    }
}

// Fused attention, 16 n-columns per block. Flat grid 800, bijective XCD swizzle.
__global__ __launch_bounds__(512) void attn_fused(const float* __restrict__ qT,
                                                  const __half* __restrict__ kpadH,
                                                  const __half* __restrict__ vpadH,
                                                  const int* __restrict__ otH,
                                                  const int* __restrict__ otD,
                                                  float* __restrict__ outT) {
    __shared__ float Plds[K2 * NT];     // 18496 B
    __shared__ float red[32 * NT];      // 2048 B
    __shared__ float colmax[NT], invl[NT];
    const int bid = blockIdx.x;
    const int wgid = (bid & 7) * 100 + (bid >> 3);
    const int h = wgid & 7;
    const int n0 = (wgid >> 3) * NT;
    const int tid = threadIdx.x;
    const int w = tid >> 6, nl = tid & 63;
    const int q4 = nl >> 4, nn = nl & 15;
    const int n = n0 + nn;
    const int basen = (n / HW) * HP + (n % HW);
    const __half* kb = kpadH + basen;
    const __half* vb = vpadH + basen;
    const int4* otHq = (const int4*)(otH + h * (K2 * 32));  // [n1*8 + k4]

    float qreg[32];
#pragma unroll
    for (int k = 0; k < 32; ++k) qreg[k] = qT[(h * 32 + k) * L + n];

    // phase B: logits. Round r: wave w, quarter q4 -> n1 = 32r + 4w + q4.
#pragma unroll 3
    for (int r = 0; r < 9; ++r) {
        const int n1 = r * 32 + w * 4 + q4;
        float a0 = 0.f, a1 = 0.f, a2 = 0.f, a3 = 0.f;
#pragma unroll
        for (int k4 = 0; k4 < 8; ++k4) {
            int4 o = otHq[n1 * 8 + k4];
            a0 = fmaf(qreg[k4 * 4 + 0], __half2float(kb[o.x]), a0);
            a1 = fmaf(qreg[k4 * 4 + 1], __half2float(kb[o.y]), a1);
            a2 = fmaf(qreg[k4 * 4 + 2], __half2float(kb[o.z]), a2);
            a3 = fmaf(qreg[k4 * 4 + 3], __half2float(kb[o.w]), a3);
        }
        Plds[n1 * NT + nn] = (a0 + a1) + (a2 + a3);
    }
    if (w * 4 + q4 == 0) {  // tail n1 = 288 (lanes 0-15 of wave 0)
        float a0 = 0.f, a1 = 0.f, a2 = 0.f, a3 = 0.f;
#pragma unroll
        for (int k4 = 0; k4 < 8; ++k4) {
            int4 o = otHq[288 * 8 + k4];
            a0 = fmaf(qreg[k4 * 4 + 0], __half2float(kb[o.x]), a0);
            a1 = fmaf(qreg[k4 * 4 + 1], __half2float(kb[o.y]), a1);
            a2 = fmaf(qreg[k4 * 4 + 2], __half2float(kb[o.z]), a2);
            a3 = fmaf(qreg[k4 * 4 + 3], __half2float(kb[o.w]), a3);
        }
        Plds[288 * NT + nn] = (a0 + a1) + (a2 + a3);
    }
    __syncthreads();

    // phase C: per-column softmax over n1; sum pre-mask, mask post (faithful).
    {
        const int col = tid & 15, seg = tid >> 4;
        float mx = -1e30f;
        for (int n1 = seg; n1 < K2; n1 += 32) mx = fmaxf(mx, Plds[n1 * NT + col]);
        red[seg * NT + col] = mx;
        __syncthreads();
        if (tid < NT) {
            float m = red[tid];
            for (int s = 1; s < 32; ++s) m = fmaxf(m, red[s * NT + tid]);
            colmax[tid] = m;
        }
        __syncthreads();
        const int ncn = n0 + col;
        const int nr = ncn / HW, nc = ncn % HW;
        const float mxc = colmax[col];
        float s = 0.f;
        for (int n1 = seg; n1 < K2; n1 += 32) {
            float e = __expf(Plds[n1 * NT + col] - mxc);
            s += e;
            int dr = n1 / KW, ds = n1 - dr * KW;
            unsigned rr = (unsigned)(nr + dr - 8), ss = (unsigned)(nc + ds - 8);
            Plds[n1 * NT + col] = (rr < HW && ss < HW) ? e : 0.f;
        }
        red[seg * NT + col] = s;
        __syncthreads();
        if (tid < NT) {
            float t = 0.f;
            for (int s2 = 0; s2 < 32; ++s2) t += red[s2 * NT + tid];
            invl[tid] = 1.f / t;
        }
        __syncthreads();
    }

    // phase D: lane = (channel mq = w*4+q4, column nn). n1 wave-uniform ->
    // P reads are LDS broadcasts; offsets via transposed table, int4 per 4 n1.
    {
        const int mq = w * 4 + q4;
        const int* otDm = otD + (h * 32 + mq) * K2P;
        float a0 = 0.f, a1 = 0.f, a2 = 0.f, a3 = 0.f;
#pragma unroll 4
        for (int t = 0; t < 72; ++t) {
            const int4 o = *(const int4*)(otDm + t * 4);
            const int nb = t * 4;
            a0 = fmaf(Plds[(nb + 0) * NT + nn], __half2float(vb[o.x]), a0);
            a1 = fmaf(Plds[(nb + 1) * NT + nn], __half2float(vb[o.y]), a1);
            a2 = fmaf(Plds[(nb + 2) * NT + nn], __half2float(vb[o.z]), a2);
            a3 = fmaf(Plds[(nb + 3) * NT + nn], __half2float(vb[o.w]), a3);
        }
        a0 = fmaf(Plds[288 * NT + nn], __half2float(vb[otDm[288]]), a0);
        const float acc = (a0 + a1) + (a2 + a3);
        outT[(h * 32 + mq) * L + n] = acc * invl[nn];
    }
}

// out[oc*1600 + l] = sum_c outT[c][l] * w[oc, c] + b[oc]   (verified r4/r7-r10)
__global__ __launch_bounds__(256) void proj_gemm(const float* __restrict__ aT,
                                                 const float* __restrict__ w,
                                                 const float* __restrict__ bias,
                                                 float* __restrict__ out) {
    __shared__ float As[16][68];  // A[c][l]
    __shared__ float Bs[16][68];  // B[c][oc]
    const int l0 = blockIdx.x * 64;
    const int oc0 = blockIdx.y * 64;
    const int tid = threadIdx.x;
    const int tx = tid & 15;   // oc quad
    const int ty = tid >> 4;   // l quad
    float acc[4][4] = {};      // [i: l][j: oc]
    for (int c0 = 0; c0 < C; c0 += 16) {
#pragma unroll
        for (int i = 0; i < 4; ++i) {
            int idx = i * 256 + tid;
            int cc = idx >> 6, ll = idx & 63;
            As[cc][ll] = aT[(c0 + cc) * L + l0 + ll];
        }
#pragma unroll
        for (int i = 0; i < 4; ++i) {
            int idx = i * 256 + tid;
            int cc = idx & 15, oo = idx >> 4;
            Bs[cc][oo] = w[(oc0 + oo) * C + c0 + cc];
        }
        __syncthreads();
#pragma unroll
        for (int kk = 0; kk < 16; ++kk) {
            float4 a = *(const float4*)&As[kk][ty * 4];
            float4 b = *(const float4*)&Bs[kk][tx * 4];
            float av[4] = {a.x, a.y, a.z, a.w};
            float bv[4] = {b.x, b.y, b.z, b.w};
#pragma unroll
            for (int i = 0; i < 4; ++i)
#pragma unroll
                for (int j = 0; j < 4; ++j)
                    acc[i][j] = fmaf(av[i], bv[j], acc[i][j]);
        }
        __syncthreads();
    }
    const int lbase = l0 + ty * 4;
#pragma unroll
    for (int j = 0; j < 4; ++j) {
        int oc = oc0 + tx * 4 + j;
        float bp = bias[oc];
        float4 v = make_float4(acc[0][j] + bp, acc[1][j] + bp,
                               acc[2][j] + bp, acc[3][j] + bp);
        *(float4*)&out[oc * L + lbase] = v;
    }
}

extern "C" void kernel_launch(void* const* d_in, const int* in_sizes, int n_in,
                              void* d_out, int out_size, void* d_ws, size_t ws_size,
                              hipStream_t stream) {
    const float* x      = (const float*)d_in[0];
    const float* w_qkv  = (const float*)d_in[1];
    const float* b_qkv  = (const float*)d_in[2];
    const float* w_proj = (const float*)d_in[3];
    const float* b_proj = (const float*)d_in[4];
    float* out = (float*)d_out;
    float* ws = (float*)d_ws;
    int*    otH   = (int*)(ws + OFF_TH);
    int*    otD   = (int*)(ws + OFF_TD);
    float*  qT    = ws + OFF_QT;   // reused as outT (disjoint lifetimes)
    __half* kpadH = (__half*)(ws + OFF_KH);
    __half* vpadH = (__half*)(ws + OFF_VH);

    // zero padded fp16 K/V images (contiguous: 2 * 802816 halves = 3.2 MB)
    hipMemsetAsync(kpadH, 0, (size_t)2 * 802816 * sizeof(__half), stream);
    addr_kernel<<<292, 256, 0, stream>>>(otH, otD);

    qkv_gemm<<<dim3(25, 12), 256, 0, stream>>>(x, w_qkv, b_qkv, qT, kpadH, vpadH);
    attn_fused<<<800, 512, 0, stream>>>(qT, kpadH, vpadH, otH, otD, qT);
    proj_gemm<<<dim3(25, 4), 256, 0, stream>>>(qT, w_proj, b_proj, out);
}

// Round 12
// 103.059 us; speedup vs baseline: 2.0217x; 1.2099x over previous
//
#include <hip/hip_runtime.h>
#include <hip/hip_fp16.h>

#define L 1600
#define C 256
#define HW 40
#define HP 56            // padded spatial (40 + 2*8)
#define HP2 (HP * HP)    // 3136
#define KW 17
#define K2 289
#define K2P 292          // K2 padded to multiple of 4 (int4 loads)
#define HEADS 8
#define NT 32            // n-columns per attn block (16 pairs)
#define NIMG 802816      // halves per padded image (256*3136)
#define NIMGU 401408     // uints per padded image
#define SCALE 0.17677669529663687f  // 32^-0.5

// workspace layout (float slots); qT reused as outT (disjoint lifetimes)
// kAll = [K image | K shifted-by-1 copy]; vAll = [V image | V shifted copy]
#define OFF_TH 0                         // otH: 8*289*32 ints = 73984
#define OFF_TD 73984                     // otD: 8*32*292 ints = 74752
#define OFF_QT 148736                    // qT/outT: 409600 f
#define OFF_KA 558336                    // kAll: 2*802816 halves = 802816 f
#define OFF_VA 1361152                   // vAll: 802816 f

// Tables with PARITY-ENCODED offsets: offE = (off&1) ? off + NIMG - 1 : off.
// Reading __half2 at (offE + even_base) is always 4B-aligned; odd offsets are
// served by the shifted copy so the pair (n, n+1) is still correct.
// otH[h][n1][i] (i = channel), otD[h][i][n1] (n1-major, padded to 292).
__global__ __launch_bounds__(256) void addr_kernel(int* __restrict__ otH,
                                                   int* __restrict__ otD) {
    int idx = blockIdx.x * 256 + threadIdx.x;   // grid = 8*292*32/256 = 292
    int h = idx / (K2P * 32);
    int rem = idx - h * (K2P * 32);
    int n1 = rem >> 5, i = rem & 31;
    int offE = 0;
    if (n1 < K2) {
        int j = n1 * 256 + h * 32 + i;
        int c = j / K2;
        int p = j - c * K2;
        int dr = p / KW;
        int off = c * HP2 + dr * HP + (p - dr * KW);
        offE = (off & 1) ? (off + NIMG - 1) : off;
        otH[(h * K2 + n1) * 32 + i] = offE;
    }
    otD[(h * 32 + i) * K2P + n1] = offE;
}

// Build shifted copies: Ks[i] = K[i+1], Vs[i] = V[i+1] (last element unused).
__global__ __launch_bounds__(256) void shift_kernel(unsigned int* __restrict__ ka) {
    int j = blockIdx.x * 256 + threadIdx.x;          // 0 .. 2*NIMGU-1
    unsigned int* img = ka + ((j < NIMGU) ? 0 : (2 * NIMGU));
    int jj = (j < NIMGU) ? j : (j - NIMGU);
    unsigned int lo = img[jj];
    unsigned int hi = (jj + 1 < NIMGU) ? img[jj + 1] : 0u;
    img[NIMGU + jj] = (lo >> 16) | (hi << 16);
}

__device__ __forceinline__ float2 gload(const __half* img, int idx) {
    __half2 hv = *reinterpret_cast<const __half2*>(img + idx);
    return make_float2(__low2float(hv), __high2float(hv));
}

// qkv[l, oc] = sum_c x[c, l] * w[oc, c] + b[oc]
// q (scaled) -> qT[m][l] f32;  k/v -> fp16 padded images  (verified r4-r11)
__global__ __launch_bounds__(256) void qkv_gemm(const float* __restrict__ x,
                                                const float* __restrict__ w,
                                                const float* __restrict__ bias,
                                                float* __restrict__ qT,
                                                __half* __restrict__ kimg,
                                                __half* __restrict__ vimg) {
    __shared__ float As[16][68];  // A[c][l]
    __shared__ float Bs[16][68];  // B[c][oc]
    const int l0 = blockIdx.x * 64;
    const int oc0 = blockIdx.y * 64;
    const int tid = threadIdx.x;
    const int tx = tid & 15;   // oc quad
    const int ty = tid >> 4;   // l quad
    float acc[4][4] = {};
    for (int c0 = 0; c0 < C; c0 += 16) {
#pragma unroll
        for (int i = 0; i < 4; ++i) {
            int idx = i * 256 + tid;
            int cc = idx >> 6, ll = idx & 63;
            As[cc][ll] = x[(c0 + cc) * L + l0 + ll];
        }
#pragma unroll
        for (int i = 0; i < 4; ++i) {
            int idx = i * 256 + tid;
            int cc = idx & 15, oo = idx >> 4;
            Bs[cc][oo] = w[(oc0 + oo) * C + c0 + cc];
        }
        __syncthreads();
#pragma unroll
        for (int kk = 0; kk < 16; ++kk) {
            float4 a = *(const float4*)&As[kk][ty * 4];
            float4 b = *(const float4*)&Bs[kk][tx * 4];
            float av[4] = {a.x, a.y, a.z, a.w};
            float bv[4] = {b.x, b.y, b.z, b.w};
#pragma unroll
            for (int i = 0; i < 4; ++i)
#pragma unroll
                for (int j = 0; j < 4; ++j)
                    acc[i][j] = fmaf(av[i], bv[j], acc[i][j]);
        }
        __syncthreads();
    }
    const int lbase = l0 + ty * 4;
    const int ocbase = oc0 + tx * 4;
    if (oc0 < 256) {
#pragma unroll
        for (int j = 0; j < 4; ++j) {
            int oc = ocbase + j;
            float b = bias[oc];
            float4 v = make_float4((acc[0][j] + b) * SCALE, (acc[1][j] + b) * SCALE,
                                   (acc[2][j] + b) * SCALE, (acc[3][j] + b) * SCALE);
            *(float4*)&qT[oc * L + lbase] = v;
        }
    } else {
        __half* dst = (oc0 < 512) ? kimg : vimg;
        const int cb = ocbase - ((oc0 < 512) ? 256 : 512);
#pragma unroll
        for (int i = 0; i < 4; ++i) {
            int l = lbase + i;
            int r = l / HW, s = l % HW;
            int base = (r + 8) * HP + (s + 8);
#pragma unroll
            for (int j = 0; j < 4; ++j)
                dst[(cb + j) * HP2 + base] = __float2half(acc[i][j] + bias[ocbase + j]);
        }
    }
}

// Fused attention, 32 n-columns per block (16 pairs), flat grid 400 with
// bijective XCD swizzle. Every gather is a __half2 = 2 consecutive n.
__global__ __launch_bounds__(512) void attn_fused(const float* __restrict__ qT,
                                                  const __half* __restrict__ kAll,
                                                  const __half* __restrict__ vAll,
                                                  const int* __restrict__ otH,
                                                  const int* __restrict__ otD,
                                                  float* __restrict__ outT) {
    __shared__ float Plds[K2 * NT];     // 36992 B
    __shared__ float red[16 * NT];      // 2048 B
    __shared__ float colmax[NT], invl[NT];
    const int bid = blockIdx.x;
    const int wgid = (bid & 7) * 50 + (bid >> 3);
    const int h = wgid & 7;
    const int n0 = (wgid >> 3) * NT;
    const int tid = threadIdx.x;
    const int w = tid >> 6, nl = tid & 63;
    const int q4 = nl >> 4, ln = nl & 15;
    const int npb = n0 + 2 * ln;                       // even
    const int base2 = (npb / HW) * HP + (npb % HW);    // even
    const int4* otHq = (const int4*)(otH + h * (K2 * 32));

    // phase B: two 16-channel passes accumulate logits into Plds.
    float2 qp[16];
    for (int pass = 0; pass < 2; ++pass) {
#pragma unroll
        for (int k = 0; k < 16; ++k)
            qp[k] = *(const float2*)&qT[(h * 32 + pass * 16 + k) * L + npb];
        auto doB = [&](int n1) {
            float c0 = 0.f, c1 = 0.f, d0 = 0.f, d1 = 0.f;
#pragma unroll
            for (int k4 = 0; k4 < 4; ++k4) {
                int4 o = otHq[n1 * 8 + pass * 4 + k4];
                float2 v0 = gload(kAll, o.x + base2);
                float2 v1 = gload(kAll, o.y + base2);
                float2 v2 = gload(kAll, o.z + base2);
                float2 v3 = gload(kAll, o.w + base2);
                c0 = fmaf(qp[k4 * 4 + 0].x, v0.x, c0);
                c1 = fmaf(qp[k4 * 4 + 0].y, v0.y, c1);
                d0 = fmaf(qp[k4 * 4 + 1].x, v1.x, d0);
                d1 = fmaf(qp[k4 * 4 + 1].y, v1.y, d1);
                c0 = fmaf(qp[k4 * 4 + 2].x, v2.x, c0);
                c1 = fmaf(qp[k4 * 4 + 2].y, v2.y, c1);
                d0 = fmaf(qp[k4 * 4 + 3].x, v3.x, d0);
                d1 = fmaf(qp[k4 * 4 + 3].y, v3.y, d1);
            }
            float2* pp = (float2*)&Plds[n1 * NT + 2 * ln];
            if (pass == 0) {
                *pp = make_float2(c0 + d0, c1 + d1);
            } else {
                float2 old = *pp;
                *pp = make_float2(old.x + c0 + d0, old.y + c1 + d1);
            }
        };
#pragma unroll 3
        for (int r = 0; r < 9; ++r) doB(r * 32 + w * 4 + q4);
        if (w * 4 + q4 == 0) doB(288);
    }
    __syncthreads();

    // phase C: per-column softmax over n1; sum pre-mask, mask post (faithful).
    {
        const int col = tid & 31, seg = tid >> 5;   // 16 segs
        float mx = -1e30f;
        for (int n1 = seg; n1 < K2; n1 += 16) mx = fmaxf(mx, Plds[n1 * NT + col]);
        red[seg * NT + col] = mx;
        __syncthreads();
        if (tid < NT) {
            float m = red[tid];
            for (int s = 1; s < 16; ++s) m = fmaxf(m, red[s * NT + tid]);
            colmax[tid] = m;
        }
        __syncthreads();
        const int ncn = n0 + col;
        const int nr = ncn / HW, nc = ncn % HW;
        const float mxc = colmax[col];
        float s = 0.f;
        for (int n1 = seg; n1 < K2; n1 += 16) {
            float e = __expf(Plds[n1 * NT + col] - mxc);
            s += e;
            int dr = n1 / KW, ds = n1 - dr * KW;
            unsigned rr = (unsigned)(nr + dr - 8), ss = (unsigned)(nc + ds - 8);
            Plds[n1 * NT + col] = (rr < HW && ss < HW) ? e : 0.f;
        }
        red[seg * NT + col] = s;
        __syncthreads();
        if (tid < NT) {
            float t = 0.f;
            for (int s2 = 0; s2 < 16; ++s2) t += red[s2 * NT + tid];
            invl[tid] = 1.f / t;
        }
        __syncthreads();
    }

    // phase D: lane = (channel mq = w*4+q4, pair ln). n1 wave-uniform ->
    // P reads are LDS float2 broadcasts; V gathers are half2 (2 n per instr).
    {
        const int mq = w * 4 + q4;
        const int* otDm = otD + (h * 32 + mq) * K2P;
        float a0 = 0.f, a1 = 0.f, a2 = 0.f, a3 = 0.f;
        float b0 = 0.f, b1 = 0.f, b2 = 0.f, b3 = 0.f;
#pragma unroll 4
        for (int t = 0; t < 72; ++t) {
            int4 o = *(const int4*)(otDm + t * 4);
            float2 p0 = *(const float2*)&Plds[(t * 4 + 0) * NT + 2 * ln];
            float2 p1 = *(const float2*)&Plds[(t * 4 + 1) * NT + 2 * ln];
            float2 p2 = *(const float2*)&Plds[(t * 4 + 2) * NT + 2 * ln];
            float2 p3 = *(const float2*)&Plds[(t * 4 + 3) * NT + 2 * ln];
            float2 v0 = gload(vAll, o.x + base2);
            float2 v1 = gload(vAll, o.y + base2);
            float2 v2 = gload(vAll, o.z + base2);
            float2 v3 = gload(vAll, o.w + base2);
            a0 = fmaf(p0.x, v0.x, a0); b0 = fmaf(p0.y, v0.y, b0);
            a1 = fmaf(p1.x, v1.x, a1); b1 = fmaf(p1.y, v1.y, b1);
            a2 = fmaf(p2.x, v2.x, a2); b2 = fmaf(p2.y, v2.y, b2);
            a3 = fmaf(p3.x, v3.x, a3); b3 = fmaf(p3.y, v3.y, b3);
        }
        {   // tail n1 = 288
            float2 p = *(const float2*)&Plds[288 * NT + 2 * ln];
            float2 v = gload(vAll, otDm[288] + base2);
            a0 = fmaf(p.x, v.x, a0); b0 = fmaf(p.y, v.y, b0);
        }
        float accA = (a0 + a1) + (a2 + a3);
        float accB = (b0 + b1) + (b2 + b3);
        float2 ov = make_float2(accA * invl[2 * ln], accB * invl[2 * ln + 1]);
        *(float2*)&outT[(h * 32 + mq) * L + npb] = ov;
    }
}

// out[oc*1600 + l] = sum_c outT[c][l] * w[oc, c] + b[oc]   (verified r4/r7-r11)
__global__ __launch_bounds__(256) void proj_gemm(const float* __restrict__ aT,
                                                 const float* __restrict__ w,
                                                 const float* __restrict__ bias,
                                                 float* __restrict__ out) {
    __shared__ float As[16][68];  // A[c][l]
    __shared__ float Bs[16][68];  // B[c][oc]
    const int l0 = blockIdx.x * 64;
    const int oc0 = blockIdx.y * 64;
    const int tid = threadIdx.x;
    const int tx = tid & 15;   // oc quad
    const int ty = tid >> 4;   // l quad
    float acc[4][4] = {};      // [i: l][j: oc]
    for (int c0 = 0; c0 < C; c0 += 16) {
#pragma unroll
        for (int i = 0; i < 4; ++i) {
            int idx = i * 256 + tid;
            int cc = idx >> 6, ll = idx & 63;
            As[cc][ll] = aT[(c0 + cc) * L + l0 + ll];
        }
#pragma unroll
        for (int i = 0; i < 4; ++i) {
            int idx = i * 256 + tid;
            int cc = idx & 15, oo = idx >> 4;
            Bs[cc][oo] = w[(oc0 + oo) * C + c0 + cc];
        }
        __syncthreads();
#pragma unroll
        for (int kk = 0; kk < 16; ++kk) {
            float4 a = *(const float4*)&As[kk][ty * 4];
            float4 b = *(const float4*)&Bs[kk][tx * 4];
            float av[4] = {a.x, a.y, a.z, a.w};
            float bv[4] = {b.x, b.y, b.z, b.w};
#pragma unroll
            for (int i = 0; i < 4; ++i)
#pragma unroll
                for (int j = 0; j < 4; ++j)
                    acc[i][j] = fmaf(av[i], bv[j], acc[i][j]);
        }
        __syncthreads();
    }
    const int lbase = l0 + ty * 4;
#pragma unroll
    for (int j = 0; j < 4; ++j) {
        int oc = oc0 + tx * 4 + j;
        float bp = bias[oc];
        float4 v = make_float4(acc[0][j] + bp, acc[1][j] + bp,
                               acc[2][j] + bp, acc[3][j] + bp);
        *(float4*)&out[oc * L + lbase] = v;
    }
}

extern "C" void kernel_launch(void* const* d_in, const int* in_sizes, int n_in,
                              void* d_out, int out_size, void* d_ws, size_t ws_size,
                              hipStream_t stream) {
    const float* x      = (const float*)d_in[0];
    const float* w_qkv  = (const float*)d_in[1];
    const float* b_qkv  = (const float*)d_in[2];
    const float* w_proj = (const float*)d_in[3];
    const float* b_proj = (const float*)d_in[4];
    float* out = (float*)d_out;
    float* ws = (float*)d_ws;
    int*    otH  = (int*)(ws + OFF_TH);
    int*    otD  = (int*)(ws + OFF_TD);
    float*  qT   = ws + OFF_QT;   // reused as outT (disjoint lifetimes)
    __half* kAll = (__half*)(ws + OFF_KA);
    __half* vAll = (__half*)(ws + OFF_VA);

    // zero K/V base+shift images (contiguous: 2 * 802816 floats worth)
    hipMemsetAsync(kAll, 0, (size_t)2 * 802816 * sizeof(float), stream);
    addr_kernel<<<292, 256, 0, stream>>>(otH, otD);

    qkv_gemm<<<dim3(25, 12), 256, 0, stream>>>(x, w_qkv, b_qkv, qT, kAll, vAll);
    shift_kernel<<<(2 * NIMGU) / 256, 256, 0, stream>>>((unsigned int*)kAll);
    attn_fused<<<400, 512, 0, stream>>>(qT, kAll, vAll, otH, otD, qT);
    proj_gemm<<<dim3(25, 4), 256, 0, stream>>>(qT, w_proj, b_proj, out);
}